// Round 6
// baseline (202.297 us; speedup 1.0000x reference)
//
#include <hip/hip_runtime.h>

// Problem constants (fixed by reference setup_inputs)
#define HW 262144    // 512*512 pixels per image
#define NB 8         // batch
#define NC 32        // channels
#define NK 8         // num classes (NUM_IDS)
#define DIST_BLOCKS 2048

typedef float f4 __attribute__((ext_vector_type(4)));

// ws layout (floats) — every slot fully overwritten each launch; ctr is
// zeroed by k_means (stream-ordered before k_dist uses it).
//   psum  [4096][8]  @ 0      per-(b,c,chunk) class channel sums
//   pcnt  [128][8]   @ 32768  per-(b,chunk) class counts
//   meansT[8][32][8] @ 33792  transposed [b][c][k]
//   counts[8][8]     @ 35840
//   pdist [2048][8]  @ 35904  per-(b,chunk) class dist sums
//   ctr   u32        @ 52288
#define WS_PSUM 0
#define WS_PCNT 32768
#define WS_MT   33792
#define WS_CNT  35840
#define WS_PD   35904
#define WS_CTR  52288

// ---------------------------------------------------------------------------
// Pass 1 (R4-verbatim): per-class channel partial sums. One block = (b, c,
// 16K-px chunk). Per-thread LDS slots (stride 9: coprime with 32 banks ->
// <=2-way aliasing, free). No atomics. b = f&7: XCD (heuristic f%8) owns one
// image -> label reads shared in that XCD's L2 across 32 channel-blocks.
// c==0 blocks also compute label counts (labels L2-hot on re-read).
// ---------------------------------------------------------------------------
__global__ __launch_bounds__(256) void k_pass1(const float* __restrict__ emb,
                                               const int* __restrict__ lab,
                                               float* __restrict__ psum,
                                               float* __restrict__ pcnt) {
    __shared__ float slots[256 * 9];
    __shared__ float red[256];
    const int t = threadIdx.x;
    const int f = blockIdx.x;
    const int b = f & 7;
    const int o = f >> 3;        // 0..511 per image
    const int chunk = o >> 5;    // 0..15
    const int c = o & 31;

    float* myslot = &slots[t * 9];
#pragma unroll
    for (int i = 0; i < 9; ++i) myslot[i] = 0.f;

    const float* e = emb + ((size_t)(b * NC + c)) * HW;
    const int* lb = lab + (size_t)b * HW;
    const int base = chunk * 16384;

    for (int it = 0; it < 16; ++it) {
        const int p = base + it * 1024 + t * 4;
        const int4 l4 = *reinterpret_cast<const int4*>(lb + p);
        const f4 e4 = __builtin_nontemporal_load(reinterpret_cast<const f4*>(e + p));
        myslot[l4.x] += e4.x;
        myslot[l4.y] += e4.y;
        myslot[l4.z] += e4.z;
        myslot[l4.w] += e4.w;
    }
    __syncthreads();

    {   // reduce slots[256][8] -> 8
        const int k = t & 7, r = t >> 3;
        float s = 0.f;
#pragma unroll
        for (int i = 0; i < 8; ++i) s += slots[(r + 32 * i) * 9 + k];
        red[r * 8 + k] = s;
    }
    __syncthreads();
    if (t < 8) {
        float s = 0.f;
#pragma unroll
        for (int r = 0; r < 32; ++r) s += red[r * 8 + t];
        psum[(size_t)f * 8 + t] = s;   // f encodes (b,c,chunk)
    }

    // counts: only c==0 blocks; labels re-read from L2
    if (c == 0) {
        __syncthreads();
#pragma unroll
        for (int i = 0; i < 9; ++i) myslot[i] = 0.f;
        for (int it = 0; it < 16; ++it) {
            const int p = base + it * 1024 + t * 4;
            const int4 l4 = *reinterpret_cast<const int4*>(lb + p);
            myslot[l4.x] += 1.f;
            myslot[l4.y] += 1.f;
            myslot[l4.z] += 1.f;
            myslot[l4.w] += 1.f;
        }
        __syncthreads();
        {
            const int k = t & 7, r = t >> 3;
            float s = 0.f;
#pragma unroll
            for (int i = 0; i < 8; ++i) s += slots[(r + 32 * i) * 9 + k];
            red[r * 8 + k] = s;
        }
        __syncthreads();
        if (t < 8) {
            float s = 0.f;
#pragma unroll
            for (int r = 0; r < 32; ++r) s += red[r * 8 + t];
            pcnt[(b * 16 + chunk) * 8 + t] = s;
        }
    }
}

// ---------------------------------------------------------------------------
// Reduce partials -> meansT [b][c][k] + counts [b][k]; block 0 zeroes the
// dist counter (stream-ordered before k_dist). R4-verbatim + ctr zero.
// ---------------------------------------------------------------------------
__global__ __launch_bounds__(256) void k_means(const float* __restrict__ psum,
                                               const float* __restrict__ pcnt,
                                               float* __restrict__ mt,
                                               float* __restrict__ cnt,
                                               unsigned int* __restrict__ ctr) {
    const int b = blockIdx.x;
    const int t = threadIdx.x;
    const int c = t >> 3, k = t & 7;

    float cn = 0.f;
#pragma unroll
    for (int ch = 0; ch < 16; ++ch) cn += pcnt[(b * 16 + ch) * 8 + k];

    float s = 0.f;
#pragma unroll
    for (int ch = 0; ch < 16; ++ch) s += psum[(size_t)(b + 8 * (c + 32 * ch)) * 8 + k];

    mt[b * 256 + c * 8 + k] = s / cn;
    if (c == 0) cnt[b * 8 + k] = cn;
    if (b == 0 && t == 0) *ctr = 0u;
}

// ---------------------------------------------------------------------------
// Pass 2 (R4 inner loop verbatim) + fused final in the last-arriving block.
// One block = (b, 1024-px chunk); 4 px/thread; means in LDS transposed
// [c][k] (lanes hit 8 distinct banks, broadcast within bank).
// ---------------------------------------------------------------------------
__global__ __launch_bounds__(256) void k_dist(const float* __restrict__ emb,
                                              const int* __restrict__ lab,
                                              const float* __restrict__ mt,
                                              const float* __restrict__ cnt,
                                              float* __restrict__ pd,
                                              unsigned int* __restrict__ ctr,
                                              float* __restrict__ out) {
    __shared__ float mT[256];
    __shared__ float slots[256 * 9];
    __shared__ float red[256];
    __shared__ float ds2[64];
    __shared__ float vv[8];
    __shared__ float hi2[168];
    __shared__ unsigned int lastFlag;
    const int t = threadIdx.x;
    const int f = blockIdx.x;
    const int b = f & 7;
    const int chunk = f >> 3;  // 0..255

    mT[t] = mt[b * 256 + t];
    float* myslot = &slots[t * 9];
#pragma unroll
    for (int i = 0; i < 9; ++i) myslot[i] = 0.f;
    __syncthreads();

    const int p = chunk * 1024 + t * 4;
    const int4 l4 = *reinterpret_cast<const int4*>(lab + (size_t)b * HW + p);
    const float* e = emb + (size_t)b * NC * HW + p;

    float a0 = 0.f, a1 = 0.f, a2 = 0.f, a3 = 0.f;
#pragma unroll 8
    for (int c = 0; c < NC; ++c) {
        const f4 e4 = __builtin_nontemporal_load(reinterpret_cast<const f4*>(e + (size_t)c * HW));
        const float* mrow = &mT[c * 8];
        const float d0 = e4.x - mrow[l4.x];
        const float d1 = e4.y - mrow[l4.y];
        const float d2 = e4.z - mrow[l4.z];
        const float d3 = e4.w - mrow[l4.w];
        a0 += d0 * d0;
        a1 += d1 * d1;
        a2 += d2 * d2;
        a3 += d3 * d3;
    }
    myslot[l4.x] += sqrtf(a0);
    myslot[l4.y] += sqrtf(a1);
    myslot[l4.z] += sqrtf(a2);
    myslot[l4.w] += sqrtf(a3);
    __syncthreads();

    {
        const int k = t & 7, r = t >> 3;
        float s = 0.f;
#pragma unroll
        for (int i = 0; i < 8; ++i) s += slots[(r + 32 * i) * 9 + k];
        red[r * 8 + k] = s;
    }
    __syncthreads();
    if (t < 8) {
        float s = 0.f;
#pragma unroll
        for (int r = 0; r < 32; ++r) s += red[r * 8 + t];
        pd[(size_t)f * 8 + t] = s;
    }
    __syncthreads();            // pd write issued by t<8; barrier drains it

    if (t == 0) {
        __threadfence();        // release: pd globally visible
        lastFlag = (atomicAdd(ctr, 1u) == DIST_BLOCKS - 1) ? 1u : 0u;
    }
    __syncthreads();
    if (lastFlag == 0u) return;
    if (t == 0) __threadfence();  // acquire
    __syncthreads();

    // ---- fused final (fixed-order sums -> deterministic) ----
    // pd flat idx = chunk*64 + b*8 + k; thread t sums flat t, t+256, ...
    // (256 = 4*64 -> residue mod 64 = t&63 = b*8+k partial)
    {
        float s = 0.f;
        for (int j = 0; j < 64; ++j) s += pd[(size_t)j * 256 + t];
        red[t] = s;
    }
    __syncthreads();
    if (t < 64)
        ds2[t] = red[t] + red[t + 64] + red[t + 128] + red[t + 192];
    __syncthreads();
    if (t < 8) {
        float v = 0.f;
#pragma unroll
        for (int k = 1; k < 8; ++k)
            v += ds2[t * 8 + k] / cnt[t * 8 + k];
        vv[t] = v;
    }
    if (t < 168) {  // 8 images x 21 pairs among clusters 1..7
        const int bb = t / 21;
        const int pr = t - bb * 21;
        int ii = 1, jj = 2, c2 = 0;
        for (int a = 1; a <= 7; ++a)
            for (int b2 = a + 1; b2 <= 7; ++b2) {
                if (c2 == pr) { ii = a; jj = b2; }
                ++c2;
            }
        const float* mTb = mt + bb * 256;
        float sq = 0.f;
#pragma unroll
        for (int c = 0; c < NC; ++c) {
            const float d = mTb[c * 8 + ii] - mTb[c * 8 + jj];
            sq += d * d;
        }
        const float dist = sqrtf(sq);
        const float gap = 5.0f - dist;  // 2*DD = 5.0
        hi2[t] = (dist < 5.0f) ? gap * gap : 0.f;
    }
    __syncthreads();
    if (t == 0) {
        float s = 0.f;
#pragma unroll
        for (int bb = 0; bb < 8; ++bb) {
            float h = 0.f;
            for (int pr = 0; pr < 21; ++pr) h += hi2[bb * 21 + pr];
            s += (vv[bb] + h * (1.0f / 6.0f)) * (1.0f / 7.0f);
        }
        out[0] = s * 0.125f;
    }
}

extern "C" void kernel_launch(void* const* d_in, const int* in_sizes, int n_in,
                              void* d_out, int out_size, void* d_ws, size_t ws_size,
                              hipStream_t stream) {
    const float* emb = (const float*)d_in[0];
    const int* lab = (const int*)d_in[1];
    float* out = (float*)d_out;
    float* ws = (float*)d_ws;

    float* psum = ws + WS_PSUM;
    float* pcnt = ws + WS_PCNT;
    float* mt = ws + WS_MT;
    float* cnt = ws + WS_CNT;
    float* pd = ws + WS_PD;
    unsigned int* ctr = (unsigned int*)(ws + WS_CTR);

    k_pass1<<<NB * 16 * NC, 256, 0, stream>>>(emb, lab, psum, pcnt);
    k_means<<<NB, 256, 0, stream>>>(psum, pcnt, mt, cnt, ctr);
    k_dist<<<DIST_BLOCKS, 256, 0, stream>>>(emb, lab, mt, cnt, pd, ctr, out);
}

// Round 7
// 106.251 us; speedup vs baseline: 1.9040x; 1.9040x over previous
//
#include <hip/hip_runtime.h>

// Problem constants (fixed by reference setup_inputs)
#define HW 262144    // 512*512 pixels per image
#define NB 8         // batch
#define NC 32        // channels
#define NK 8         // num classes (NUM_IDS)

typedef float f4 __attribute__((ext_vector_type(4)));

// ws layout (floats) — every slot fully overwritten each launch, no init,
// no atomics anywhere. Total 50176 floats = 196 KB.
//   psum [4096][8] @ 0      per-(b,c,chunk) class channel sums
//   pcnt [128][8]  @ 32768  per-(b,chunk) class counts
//   pd   [2048][8] @ 33792  per-(b,chunk) class dist sums
#define WS_PSUM 0
#define WS_PCNT 32768
#define WS_PD   33792

// ---------------------------------------------------------------------------
// Pass 1 (R4-verbatim): per-class channel partial sums. One block = (b, c,
// 16K-px chunk). Per-thread LDS slots (stride 9: coprime with 32 banks ->
// <=2-way aliasing, free). No atomics. b = f&7: XCD (heuristic f%8) owns one
// image -> label reads shared in that XCD's L2 across 32 channel-blocks.
// c==0 blocks also compute label counts (labels L2-hot on re-read).
// ---------------------------------------------------------------------------
__global__ __launch_bounds__(256) void k_pass1(const float* __restrict__ emb,
                                               const int* __restrict__ lab,
                                               float* __restrict__ psum,
                                               float* __restrict__ pcnt) {
    __shared__ float slots[256 * 9];
    __shared__ float red[256];
    const int t = threadIdx.x;
    const int f = blockIdx.x;
    const int b = f & 7;
    const int o = f >> 3;        // 0..511 per image
    const int chunk = o >> 5;    // 0..15
    const int c = o & 31;

    float* myslot = &slots[t * 9];
#pragma unroll
    for (int i = 0; i < 9; ++i) myslot[i] = 0.f;

    const float* e = emb + ((size_t)(b * NC + c)) * HW;
    const int* lb = lab + (size_t)b * HW;
    const int base = chunk * 16384;

    for (int it = 0; it < 16; ++it) {
        const int p = base + it * 1024 + t * 4;
        const int4 l4 = *reinterpret_cast<const int4*>(lb + p);
        const f4 e4 = __builtin_nontemporal_load(reinterpret_cast<const f4*>(e + p));
        myslot[l4.x] += e4.x;
        myslot[l4.y] += e4.y;
        myslot[l4.z] += e4.z;
        myslot[l4.w] += e4.w;
    }
    __syncthreads();

    {   // reduce slots[256][8] -> 8
        const int k = t & 7, r = t >> 3;
        float s = 0.f;
#pragma unroll
        for (int i = 0; i < 8; ++i) s += slots[(r + 32 * i) * 9 + k];
        red[r * 8 + k] = s;
    }
    __syncthreads();
    if (t < 8) {
        float s = 0.f;
#pragma unroll
        for (int r = 0; r < 32; ++r) s += red[r * 8 + t];
        psum[(size_t)f * 8 + t] = s;   // f encodes (b,c,chunk)
    }

    // counts: only c==0 blocks; labels re-read from L2
    if (c == 0) {
        __syncthreads();
#pragma unroll
        for (int i = 0; i < 9; ++i) myslot[i] = 0.f;
        for (int it = 0; it < 16; ++it) {
            const int p = base + it * 1024 + t * 4;
            const int4 l4 = *reinterpret_cast<const int4*>(lb + p);
            myslot[l4.x] += 1.f;
            myslot[l4.y] += 1.f;
            myslot[l4.z] += 1.f;
            myslot[l4.w] += 1.f;
        }
        __syncthreads();
        {
            const int k = t & 7, r = t >> 3;
            float s = 0.f;
#pragma unroll
            for (int i = 0; i < 8; ++i) s += slots[(r + 32 * i) * 9 + k];
            red[r * 8 + k] = s;
        }
        __syncthreads();
        if (t < 8) {
            float s = 0.f;
#pragma unroll
            for (int r = 0; r < 32; ++r) s += red[r * 8 + t];
            pcnt[(b * 16 + chunk) * 8 + t] = s;
        }
    }
}

// ---------------------------------------------------------------------------
// Pass 2 (R4 inner loop verbatim). Head change: each block computes its
// image's means from psum/pcnt directly (16 KB of L2-resident reads,
// thread t owns (c,k) = (t>>3, t&7)), removing the k_means dispatch.
// One block = (b, 1024-px chunk); 4 px/thread; means in LDS transposed
// [c][k] (8 consecutive words -> 8 distinct banks, broadcast within bank).
// Block writes its own pd slot — no atomics.
// ---------------------------------------------------------------------------
__global__ __launch_bounds__(256) void k_dist(const float* __restrict__ emb,
                                              const int* __restrict__ lab,
                                              const float* __restrict__ psum,
                                              const float* __restrict__ pcnt,
                                              float* __restrict__ pd) {
    __shared__ float mT[256];
    __shared__ float slots[256 * 9];
    __shared__ float red[256];
    const int t = threadIdx.x;
    const int f = blockIdx.x;
    const int b = f & 7;
    const int chunk = f >> 3;  // 0..255

    // --- means head (replaces the k_means kernel) ---
    {
        const int c = t >> 3, k = t & 7;
        float cn = 0.f;
#pragma unroll
        for (int ch = 0; ch < 16; ++ch) cn += pcnt[(b * 16 + ch) * 8 + k];
        float s = 0.f;
#pragma unroll
        for (int ch = 0; ch < 16; ++ch) s += psum[(size_t)(b + 8 * (c + 32 * ch)) * 8 + k];
        mT[c * 8 + k] = s / cn;
    }
    float* myslot = &slots[t * 9];
#pragma unroll
    for (int i = 0; i < 9; ++i) myslot[i] = 0.f;
    __syncthreads();

    const int p = chunk * 1024 + t * 4;
    const int4 l4 = *reinterpret_cast<const int4*>(lab + (size_t)b * HW + p);
    const float* e = emb + (size_t)b * NC * HW + p;

    float a0 = 0.f, a1 = 0.f, a2 = 0.f, a3 = 0.f;
#pragma unroll 8
    for (int c = 0; c < NC; ++c) {
        const f4 e4 = __builtin_nontemporal_load(reinterpret_cast<const f4*>(e + (size_t)c * HW));
        const float* mrow = &mT[c * 8];
        const float d0 = e4.x - mrow[l4.x];
        const float d1 = e4.y - mrow[l4.y];
        const float d2 = e4.z - mrow[l4.z];
        const float d3 = e4.w - mrow[l4.w];
        a0 += d0 * d0;
        a1 += d1 * d1;
        a2 += d2 * d2;
        a3 += d3 * d3;
    }
    myslot[l4.x] += sqrtf(a0);
    myslot[l4.y] += sqrtf(a1);
    myslot[l4.z] += sqrtf(a2);
    myslot[l4.w] += sqrtf(a3);
    __syncthreads();

    {
        const int k = t & 7, r = t >> 3;
        float s = 0.f;
#pragma unroll
        for (int i = 0; i < 8; ++i) s += slots[(r + 32 * i) * 9 + k];
        red[r * 8 + k] = s;
    }
    __syncthreads();
    if (t < 8) {
        float s = 0.f;
#pragma unroll
        for (int r = 0; r < 32; ++r) s += red[r * 8 + t];
        pd[(size_t)f * 8 + t] = s;
    }
}

// ---------------------------------------------------------------------------
// Epilogue (1 block): recompute counts+means into LDS (L2-resident reads),
// coalesced pd reduce, var + hinge. Fixed-order sums -> deterministic.
// ---------------------------------------------------------------------------
__global__ __launch_bounds__(256) void k_final(const float* __restrict__ psum,
                                               const float* __restrict__ pcnt,
                                               const float* __restrict__ pd,
                                               float* __restrict__ out) {
    __shared__ float mtAll[8 * 256];  // [b][c*8+k]
    __shared__ float cntS[64];        // [b][k]
    __shared__ float red[256];
    __shared__ float ds2[64];
    __shared__ float vv[8];
    __shared__ float hi2[168];
    const int t = threadIdx.x;

    if (t < 64) {
        const int b = t >> 3, k = t & 7;
        float cn = 0.f;
#pragma unroll
        for (int ch = 0; ch < 16; ++ch) cn += pcnt[(b * 16 + ch) * 8 + k];
        cntS[t] = cn;
    }
    __syncthreads();
    {
        const int c = t >> 3, k = t & 7;
        for (int b = 0; b < 8; ++b) {
            float s = 0.f;
#pragma unroll
            for (int ch = 0; ch < 16; ++ch) s += psum[(size_t)(b + 8 * (c + 32 * ch)) * 8 + k];
            mtAll[b * 256 + c * 8 + k] = s / cntS[b * 8 + k];
        }
    }

    // pd reduce: flat idx = chunk*64 + b*8 + k; thread t sums t, t+256, ...
    // (residue mod 64 = b*8+k); lane-contiguous -> coalesced.
    {
        float s = 0.f;
        for (int j = 0; j < 64; ++j) s += pd[(size_t)j * 256 + t];
        red[t] = s;
    }
    __syncthreads();
    if (t < 64)
        ds2[t] = red[t] + red[t + 64] + red[t + 128] + red[t + 192];
    __syncthreads();

    if (t < 8) {
        float v = 0.f;
#pragma unroll
        for (int k = 1; k < 8; ++k)
            v += ds2[t * 8 + k] / cntS[t * 8 + k];
        vv[t] = v;
    }
    if (t < 168) {  // 8 images x 21 pairs among clusters 1..7
        const int bb = t / 21;
        const int pr = t - bb * 21;
        int ii = 1, jj = 2, c2 = 0;
        for (int a = 1; a <= 7; ++a)
            for (int b2 = a + 1; b2 <= 7; ++b2) {
                if (c2 == pr) { ii = a; jj = b2; }
                ++c2;
            }
        const float* mTb = &mtAll[bb * 256];
        float sq = 0.f;
#pragma unroll
        for (int c = 0; c < NC; ++c) {
            const float d = mTb[c * 8 + ii] - mTb[c * 8 + jj];
            sq += d * d;
        }
        const float dist = sqrtf(sq);
        const float gap = 5.0f - dist;  // 2*DD = 5.0
        hi2[t] = (dist < 5.0f) ? gap * gap : 0.f;
    }
    __syncthreads();
    if (t == 0) {
        float s = 0.f;
#pragma unroll
        for (int bb = 0; bb < 8; ++bb) {
            float h = 0.f;
            for (int pr = 0; pr < 21; ++pr) h += hi2[bb * 21 + pr];
            s += (vv[bb] + h * (1.0f / 6.0f)) * (1.0f / 7.0f);
        }
        out[0] = s * 0.125f;
    }
}

extern "C" void kernel_launch(void* const* d_in, const int* in_sizes, int n_in,
                              void* d_out, int out_size, void* d_ws, size_t ws_size,
                              hipStream_t stream) {
    const float* emb = (const float*)d_in[0];
    const int* lab = (const int*)d_in[1];
    float* out = (float*)d_out;
    float* ws = (float*)d_ws;

    float* psum = ws + WS_PSUM;
    float* pcnt = ws + WS_PCNT;
    float* pd = ws + WS_PD;

    k_pass1<<<NB * 16 * NC, 256, 0, stream>>>(emb, lab, psum, pcnt);
    k_dist<<<NB * 256, 256, 0, stream>>>(emb, lab, psum, pcnt, pd);
    k_final<<<1, 256, 0, stream>>>(psum, pcnt, pd, out);
}